// Round 13
// baseline (141.788 us; speedup 1.0000x reference)
//
#include <hip/hip_runtime.h>
#include <stdint.h>

// LinearBin: out = x @ sign(W)^T + bias   (B=131072, IN=OUT=512, fp32)
// v13: strict-FIFO counted-vmcnt pipeline. Per-wave VMEM issue order equals
//      consumption order: DMA(0),B(0),DMA(1),B(1),... so no compiler B-wait
//      ever retires a future chunk's DMA (v12's hidden stall). Full-chunk B
//      double-buffer, 16-slot LDS swizzle (2-way = free), setprio around
//      MFMA clusters. 8 waves x (64x64 tile), 64KB LDS ring, 1 block/CU.

#define BATCH   131072
#define IN_F    512
#define OUT_F   512
#define BM      64
#define NCH     8             // K-chunks of 64 floats (4 mfma k-steps each)
#define BUFB    16384         // bytes per ring buffer

using f32x4  = __attribute__((ext_vector_type(4))) float;
using f32x16 = __attribute__((ext_vector_type(16))) float;
using short8 = __attribute__((ext_vector_type(8))) short;
using usv8   = __attribute__((ext_vector_type(8))) unsigned short;
using u32    = uint32_t;

// ---------------- prep: binarize W into 32x32x16-fragment-major bf16 --------
// (verified r6/r8)  wf[((kt*16+nf)*64+l)*8+j] = sign(W[nf*32+(l&31)][kt*16+(l>>5)*8+j])
__global__ void prep_w(const float* __restrict__ W, unsigned short* __restrict__ wf) {
    int t = blockIdx.x * blockDim.x + threadIdx.x; // 32768 threads
    int l  = t & 63;
    int nf = (t >> 6) & 15;
    int kt = t >> 10;
    int n = nf * 32 + (l & 31);
    int k = kt * 16 + ((l >> 5) << 3);
    const float* src = W + (size_t)n * IN_F + k;
    f32x4 w0 = *(const f32x4*)(src);
    f32x4 w1 = *(const f32x4*)(src + 4);
    usv8 o;
#pragma unroll
    for (int j = 0; j < 4; ++j) {
        o[j]     = (w0[j] >= 0.0f) ? 0x3F80u : 0xBF80u; // +1.0 / -1.0 bf16
        o[j + 4] = (w1[j] >= 0.0f) ? 0x3F80u : 0xBF80u;
    }
    *(usv8*)(wf + (size_t)t * 8) = o;
}

// ---------------- GEMM ----------------
__global__ __launch_bounds__(512, 2) void gemm_bin(
    const float* __restrict__ X, const unsigned short* __restrict__ WF,
    const float* __restrict__ bias, float* __restrict__ out) {

    // ring of 4 fp32 chunks: [64 rows][256B], 16B slots XOR-swizzled by row&15
    __shared__ __align__(16) char smem[4 * BUFB];   // 64KB

    const int tid  = threadIdx.x;
    const int lane = tid & 63;
    const int wv   = tid >> 6;              // 0..7 -> 64-col strip
    const int m0   = blockIdx.x * BM;       // grid = 2048

    // ---- DMA source geometry (2 x 16B per thread per chunk) ----
    // lin LDS off = wv*1024 + lane*16 -> row = wv*4 + (lane>>4), slot = lane&15
    // content: LDS[r][s] = x[m0+r][ck*64 + 4*(s ^ (r&15))]
    const int dr   = wv * 4 + (lane >> 4);
    const int ds4  = ((lane & 15) ^ (dr & 15)) << 2;   // float offset in row
    const float* src0 = X + (size_t)(m0 + dr) * IN_F + ds4;
    const float* src1 = src0 + (size_t)32 * IN_F;      // (dr+32)&15 == dr&15

#define ISSUE_DMA(ck_)                                                         \
    {                                                                          \
        char* b_ = smem + ((ck_) & 3) * BUFB + wv * 1024;                      \
        __builtin_amdgcn_global_load_lds(                                      \
            (const __attribute__((address_space(1))) void*)(src0 + (ck_) * 64),\
            (__attribute__((address_space(3))) void*)(b_), 16, 0, 0);          \
        __builtin_amdgcn_global_load_lds(                                      \
            (const __attribute__((address_space(1))) void*)(src1 + (ck_) * 64),\
            (__attribute__((address_space(3))) void*)(b_ + 8192), 16, 0, 0);   \
    }

    // ---- B geometry: fragment-major, nf = wv*2+fn (verified r6/r8) ----
    const short8* wb = (const short8*)(WF) + ((size_t)(wv * 2) * 64 + lane);
    short8 bf[2][4][2];
#define LDB_ALL(bi_, ck_)                                                      \
    {                                                                          \
        _Pragma("unroll")                                                      \
        for (int g = 0; g < 4; ++g)                                            \
            _Pragma("unroll")                                                  \
            for (int fn = 0; fn < 2; ++fn)                                     \
                bf[bi_][g][fn] = wb[((ck_) * 4 + g) * 1024 + fn * 64];         \
    }

    // ---- A-frag: lane l -> row rg*32+(l&31), floats kt4*16+(l>>5)*8 ----
    // lin slot byte = ((kt4*4 + 2*(l>>5))<<4) ^ ((row&15)<<4); hi = lo^16
    const int arow = (lane & 31) * 256;
    const int aq32 = (lane >> 5) << 5;
    const int aswz = (lane & 15) << 4;

#define LDA_CVT(dst, ab_, kt4_)                                                \
    {                                                                          \
        _Pragma("unroll")                                                      \
        for (int rg = 0; rg < 2; ++rg) {                                       \
            const char* p_  = (ab_) + rg * 8192 + arow;                        \
            const int  blo_ = (((kt4_) << 6) + aq32) ^ aswz;                   \
            f32x4 lo_ = *(const f32x4*)(p_ + blo_);                            \
            f32x4 hi_ = *(const f32x4*)(p_ + (blo_ ^ 16));                     \
            u32 w0_, w1_, w2_, w3_;                                            \
            asm("v_cvt_pk_bf16_f32 %0, %1, %2" : "=v"(w0_)                     \
                : "v"(lo_[0]), "v"(lo_[1]));                                   \
            asm("v_cvt_pk_bf16_f32 %0, %1, %2" : "=v"(w1_)                     \
                : "v"(lo_[2]), "v"(lo_[3]));                                   \
            asm("v_cvt_pk_bf16_f32 %0, %1, %2" : "=v"(w2_)                     \
                : "v"(hi_[0]), "v"(hi_[1]));                                   \
            asm("v_cvt_pk_bf16_f32 %0, %1, %2" : "=v"(w3_)                     \
                : "v"(hi_[2]), "v"(hi_[3]));                                   \
            union { u32 w[4]; short8 v; } pk_;                                 \
            pk_.w[0] = w0_; pk_.w[1] = w1_; pk_.w[2] = w2_; pk_.w[3] = w3_;    \
            dst[rg] = pk_.v;                                                   \
        }                                                                      \
    }

    // ---- bias -> accumulator init (VMEM bias loads retire here) ----
    f32x16 acc[2][2];
#pragma unroll
    for (int fn = 0; fn < 2; ++fn) {
        const float bv = bias[wv * 64 + fn * 32 + (lane & 31)];
#pragma unroll
        for (int rg = 0; rg < 2; ++rg)
#pragma unroll
            for (int r = 0; r < 16; ++r) acc[rg][fn][r] = bv;
    }
    __builtin_amdgcn_sched_barrier(0);

    // ---- prologue: FIFO ladder  DMA(0), B(0), DMA(1) ----
    ISSUE_DMA(0);
    __builtin_amdgcn_sched_barrier(0);
    LDB_ALL(0, 0);
    __builtin_amdgcn_sched_barrier(0);
    ISSUE_DMA(1);
    __builtin_amdgcn_sched_barrier(0);

#pragma unroll
    for (int ck = 0; ck < NCH; ++ck) {
        // 1. prefetch next chunk's B (keeps FIFO order: ...DMA(ck+1), B(ck+1))
        if (ck + 1 < NCH) LDB_ALL((ck + 1) & 1, ck + 1);
        __builtin_amdgcn_sched_barrier(0);
        // 2. retire exactly DMA(ck):
        //    in flight: DMA(ck)2 + B(ck)8 + [DMA(ck+1)2 + B(ck+1)8] = 20 | 10
        if (ck < NCH - 1) asm volatile("s_waitcnt vmcnt(18)" ::: "memory");
        else              asm volatile("s_waitcnt vmcnt(8)"  ::: "memory");
        __builtin_amdgcn_sched_barrier(0);
        __builtin_amdgcn_s_barrier();
        __builtin_amdgcn_sched_barrier(0);
        // 3. top up the ring (newest in FIFO; nothing waits on it this chunk)
        if (ck + 2 < NCH) ISSUE_DMA(ck + 2);
        __builtin_amdgcn_sched_barrier(0);

        // 4. compute chunk ck
        const char* ab = smem + (ck & 3) * BUFB;
        short8 af[2];
#pragma unroll
        for (int kt4 = 0; kt4 < 4; ++kt4) {
            LDA_CVT(af, ab, kt4);
            __builtin_amdgcn_s_setprio(1);
#pragma unroll
            for (int rg = 0; rg < 2; ++rg)
#pragma unroll
                for (int fn = 0; fn < 2; ++fn)
                    acc[rg][fn] = __builtin_amdgcn_mfma_f32_32x32x16_bf16(
                        af[rg], bf[ck & 1][kt4][fn], acc[rg][fn], 0, 0, 0);
            __builtin_amdgcn_s_setprio(0);
        }
    }
#undef ISSUE_DMA
#undef LDB_ALL
#undef LDA_CVT

    // ---- epilogue: direct stores (bias already in acc) ----
    // C/D: col = lane&31, row = (r&3) + 8*(r>>2) + 4*(lane>>5)
    const int c     = lane & 31;
    const int rbase = (lane >> 5) << 2;
#pragma unroll
    for (int rg = 0; rg < 2; ++rg)
#pragma unroll
        for (int fn = 0; fn < 2; ++fn)
#pragma unroll
            for (int r = 0; r < 16; ++r) {
                const int row = rg * 32 + (r & 3) + 8 * (r >> 2) + rbase;
                out[(size_t)(m0 + row) * OUT_F + wv * 64 + fn * 32 + c] =
                    acc[rg][fn][r];
            }
}

extern "C" void kernel_launch(void* const* d_in, const int* in_sizes, int n_in,
                              void* d_out, int out_size, void* d_ws, size_t ws_size,
                              hipStream_t stream) {
    const float* X    = (const float*)d_in[0];
    const float* W    = (const float*)d_in[1];
    const float* bias = (const float*)d_in[2];
    float* o          = (float*)d_out;
    unsigned short* wf = (unsigned short*)d_ws; // 512KB fragment-major binarized W

    hipLaunchKernelGGL(prep_w, dim3(128), dim3(256), 0, stream, W, wf);
    hipLaunchKernelGGL(gemm_bin, dim3(BATCH / BM), dim3(512), 0, stream,
                       X, wf, bias, o);
}